// Round 6
// baseline (294.523 us; speedup 1.0000x reference)
//
#include <hip/hip_runtime.h>
#include <hip/hip_bf16.h>
#include <stdint.h>

typedef short bf16x8 __attribute__((ext_vector_type(8)));
typedef float f32x4 __attribute__((ext_vector_type(4)));
typedef __attribute__((address_space(3))) void lds_void_t;
typedef __attribute__((address_space(1))) void g_void_t;

static __device__ __forceinline__ unsigned short f2b(float f) {
    __hip_bfloat16 b = __float2bfloat16(f);
    return __builtin_bit_cast(unsigned short, b);
}
static __device__ __forceinline__ float b2f(unsigned int u) {
    return __builtin_bit_cast(float, u << 16);
}

// ---------------- fused prep: cast x + 4 weights to bf16, concat biases ----
__global__ __launch_bounds__(256) void prep(
    const float* __restrict__ x,
    const float* __restrict__ wq, const float* __restrict__ wk,
    const float* __restrict__ wv, const float* __restrict__ wo,
    const float* __restrict__ bq, const float* __restrict__ bk,
    const float* __restrict__ bv_, float* __restrict__ bqkv,
    ushort* __restrict__ xb, ushort* __restrict__ wqkvb)
{
    const int T = 3145728;  // float4 units: x 2097152 + 4 * 262144
    int i = blockIdx.x * 256 + threadIdx.x;
    const int stride = gridDim.x * 256;
    for (; i < T; i += stride) {
        const float* src; ushort* dst; int off;
        if (i < 2097152) { src = x; dst = xb; off = i; }
        else {
            const int j = i - 2097152;
            const int w = j >> 18;
            off = j & 262143;
            src = (w == 0) ? wq : (w == 1) ? wk : (w == 2) ? wv : wo;
            dst = wqkvb + (w << 20);
        }
        float4 v = reinterpret_cast<const float4*>(src)[off];
        ushort4 o;
        o.x = f2b(v.x); o.y = f2b(v.y); o.z = f2b(v.z); o.w = f2b(v.w);
        reinterpret_cast<ushort4*>(dst)[off] = o;
    }
    const int t = blockIdx.x * 256 + threadIdx.x;
    if (t < 3072) {
        const int sec = t >> 10, of = t & 1023;
        bqkv[t] = sec == 0 ? bq[of] : (sec == 1 ? bk[of] : bv_[of]);
    }
}

// ============ 256x256 8-wave phased bf16 GEMM, C = (A*B^T + bias)*alpha ====
// A: [M][lda], B: [N][ldb] bf16 (K contiguous). bf16 out via swizzled LDS
// bounce. grid (N/256, M/256, batch), block 512 (8 waves, 2M x 4N).
// Schedule: per K-tile, 4 zigzag quadrant phases; each phase ds-reads its
// fragments, issues 2 global_load_lds for tile t+1 (other buffer), runs 16
// MFMA under setprio(1). One __syncthreads per K-tile (vmcnt/lgkm drain).
// Race-safety: stages write buf[cur^1]; all reads of buf[cur^1] completed
// before the PREVIOUS barrier (lgkm drained there), so write-after-read is
// barrier-ordered; reads of buf[cur] see loads drained at the last barrier.
template<bool HAS_BIAS>
__global__ __launch_bounds__(512, 2)
void gemm256_bt(const ushort* __restrict__ A, const ushort* __restrict__ B,
                const float* __restrict__ bias, ushort* __restrict__ C,
                int lda, int ldb, int ldc, int K,
                long strideA, long strideB, long strideC, float alpha)
{
    __shared__ __align__(16) ushort smem[2][2][16384];   // [buf][A|B][256*64]

    const int bz = blockIdx.z;
    A += (size_t)bz * strideA;
    B += (size_t)bz * strideB;
    C += (size_t)bz * strideC;

    // XCD swizzle (per z-plane)
    const int gx = gridDim.x, gy = gridDim.y;
    const int nwg = gx * gy;
    int bx = blockIdx.x, by = blockIdx.y;
    if ((nwg & 7) == 0) {
        const int flat = blockIdx.x + gx * blockIdx.y;
        const int cpx = nwg >> 3;
        const int u = (flat & 7) * cpx + (flat >> 3);
        bx = u % gx;
        by = u / gx;
    }

    const int tid = threadIdx.x;
    const int w   = tid >> 6;      // wave 0..7
    const int l   = tid & 63;
    const int wr  = w >> 2;        // 0..1  (M half)
    const int wc  = w & 3;         // 0..3  (N quarter)

    const int bRow = by * 256;
    const int bCol = bx * 256;

    // staging lane addressing: chunk = 8 rows x 64 k = 1KB;
    // LDS[row][slot16] = global[row][slot16 ^ (row&7)] via pre-swizzled src.
    const int lr   = l >> 3;
    const int scol = (((l & 7) ^ lr) << 3);

    f32x4 acc[8][4];
#pragma unroll
    for (int m = 0; m < 8; ++m)
#pragma unroll
        for (int n = 0; n < 4; ++n)
            acc[m][n] = f32x4{0.f, 0.f, 0.f, 0.f};

    const int NT = K >> 6;

    // prologue: stage K-tile 0 into buf 0 (each wave: 4 A-chunks + 4 B-chunks)
#pragma unroll
    for (int p = 0; p < 4; ++p) {
        const int c = w * 4 + p;
        const ushort* gA = A + (size_t)(bRow + c * 8 + lr) * lda + scol;
        const ushort* gB = B + (size_t)(bCol + c * 8 + lr) * ldb + scol;
        __builtin_amdgcn_global_load_lds((const g_void_t*)gA,
            (lds_void_t*)((char*)&smem[0][0][0] + c * 1024), 16, 0, 0);
        __builtin_amdgcn_global_load_lds((const g_void_t*)gB,
            (lds_void_t*)((char*)&smem[0][1][0] + c * 1024), 16, 0, 0);
    }
    __syncthreads();

    int cur = 0;
    bf16x8 af[4][2], bfr[2][2];
    for (int t = 0; t < NT; ++t) {
        const char* sAc = (const char*)&smem[cur][0][0];
        const char* sBc = (const char*)&smem[cur][1][0];
        char* sAn = (char*)&smem[cur ^ 1][0][0];
        char* sBn = (char*)&smem[cur ^ 1][1][0];
        const int k1  = (t + 1) << 6;
        const bool pre = (t + 1 < NT);

#pragma unroll
        for (int p = 0; p < 4; ++p) {
            const int mh = p >> 1;                      // zigzag: 00,01,11,10
            const int nh = (p == 1 || p == 2) ? 1 : 0;
            if (p == 0 || p == 2) {
#pragma unroll
                for (int i = 0; i < 4; ++i) {
                    const int ar = wr * 128 + (mh * 4 + i) * 16 + (l & 15);
#pragma unroll
                    for (int ks = 0; ks < 2; ++ks) {
                        const int slot = (ks * 4 + (l >> 4)) ^ (ar & 7);
                        af[i][ks] = *reinterpret_cast<const bf16x8*>(
                            sAc + ar * 128 + slot * 16);
                    }
                }
            }
            if (p != 2) {
#pragma unroll
                for (int j = 0; j < 2; ++j) {
                    const int br = wc * 64 + (nh * 2 + j) * 16 + (l & 15);
#pragma unroll
                    for (int ks = 0; ks < 2; ++ks) {
                        const int slot = (ks * 4 + (l >> 4)) ^ (br & 7);
                        bfr[j][ks] = *reinterpret_cast<const bf16x8*>(
                            sBc + br * 128 + slot * 16);
                    }
                }
            }
            if (pre) {
                const int c = w * 4 + p;
                const ushort* gA = A + (size_t)(bRow + c * 8 + lr) * lda + (k1 + scol);
                const ushort* gB = B + (size_t)(bCol + c * 8 + lr) * ldb + (k1 + scol);
                __builtin_amdgcn_global_load_lds((const g_void_t*)gA,
                    (lds_void_t*)(sAn + c * 1024), 16, 0, 0);
                __builtin_amdgcn_global_load_lds((const g_void_t*)gB,
                    (lds_void_t*)(sBn + c * 1024), 16, 0, 0);
            }
            __builtin_amdgcn_s_setprio(1);
#pragma unroll
            for (int ks = 0; ks < 2; ++ks)
#pragma unroll
                for (int i = 0; i < 4; ++i)
#pragma unroll
                    for (int j = 0; j < 2; ++j)
                        acc[mh * 4 + i][nh * 2 + j] =
                            __builtin_amdgcn_mfma_f32_16x16x32_bf16(
                                af[i][ks], bfr[j][ks],
                                acc[mh * 4 + i][nh * 2 + j], 0, 0, 0);
            __builtin_amdgcn_s_setprio(0);
            __builtin_amdgcn_sched_barrier(0);
        }
        __syncthreads();
        cur ^= 1;
    }

    // epilogue: swizzled LDS bounce (256x256 bf16 = 128 KB, exact fit)
    ushort* st = (ushort*)smem;
    const int cl = l & 15;
#pragma unroll
    for (int n = 0; n < 4; ++n) {
        const int col = wc * 64 + n * 16 + cl;
        const float bv = HAS_BIAS ? bias[bCol + col] : 0.f;
#pragma unroll
        for (int m = 0; m < 8; ++m) {
            const int row0 = wr * 128 + m * 16 + (l >> 4) * 4;
#pragma unroll
            for (int r = 0; r < 4; ++r) {
                const int row = row0 + r;
                const int sl  = ((col >> 3) ^ (row & 7));
                st[row * 256 + (sl << 3) + (col & 7)] =
                    f2b((acc[m][n][r] + bv) * alpha);
            }
        }
    }
    __syncthreads();
#pragma unroll
    for (int i = 0; i < 16; ++i) {
        const int c    = tid + (i << 9);
        const int row  = c >> 5;
        const int slot = (c & 31) ^ (row & 7);
        const uint4 v = *reinterpret_cast<const uint4*>(
            (const char*)st + row * 512 + slot * 16);
        *reinterpret_cast<uint4*>(
            C + (size_t)(bRow + row) * ldc + bCol + ((c & 31) << 3)) = v;
    }
}

// ---------------- 128x128 bf16 GEMM (proven), C = (A*B^T + bias)*alpha ----
template<typename CT, bool HAS_BIAS>
__global__ __launch_bounds__(256, 4)
void gemm_bt(const ushort* __restrict__ A, const ushort* __restrict__ B,
             const float* __restrict__ bias, CT* __restrict__ C,
             int lda, int ldb, int ldc, int K,
             long strideA, long strideB, long strideC, float alpha)
{
    __shared__ __align__(16) ushort smem[128 * 64 * 2];   // 32 KB
    ushort* sA = smem;
    ushort* sB = smem + 128 * 64;

    const int bz = blockIdx.z;
    A += (size_t)bz * strideA;
    B += (size_t)bz * strideB;
    C += (size_t)bz * strideC;

    const int gx = gridDim.x, gy = gridDim.y;
    const int nwg = gx * gy;
    int bx = blockIdx.x, by = blockIdx.y;
    if ((nwg & 7) == 0) {
        const int flat = blockIdx.x + gx * blockIdx.y;
        const int cpx = nwg >> 3;
        const int u = (flat & 7) * cpx + (flat >> 3);
        bx = u % gx;
        by = u / gx;
    }

    const int tid = threadIdx.x;
    const int w   = tid >> 6;
    const int l   = tid & 63;
    const int wr  = w >> 1;
    const int wc  = w & 1;

    const int bRow = by * 128;
    const int bCol = bx * 128;

    const int lr   = l >> 3;
    const int scol = (((l & 7) ^ lr) << 3);

    f32x4 acc[4][4];
#pragma unroll
    for (int m = 0; m < 4; ++m)
#pragma unroll
        for (int n = 0; n < 4; ++n)
            acc[m][n] = f32x4{0.f, 0.f, 0.f, 0.f};

    for (int k0 = 0; k0 < K; k0 += 64) {
#pragma unroll
        for (int p = 0; p < 4; ++p) {
            const int c   = p * 4 + w;
            const int row = c * 8 + lr;
            const ushort* gA = A + (size_t)(bRow + row) * lda + (k0 + scol);
            const ushort* gB = B + (size_t)(bCol + row) * ldb + (k0 + scol);
            __builtin_amdgcn_global_load_lds((const g_void_t*)gA,
                (lds_void_t*)((char*)sA + c * 1024), 16, 0, 0);
            __builtin_amdgcn_global_load_lds((const g_void_t*)gB,
                (lds_void_t*)((char*)sB + c * 1024), 16, 0, 0);
        }
        __syncthreads();

        bf16x8 af[4][2], bfv[4][2];
#pragma unroll
        for (int m = 0; m < 4; ++m) {
            const int ar = wr * 64 + m * 16 + (l & 15);
#pragma unroll
            for (int ks = 0; ks < 2; ++ks) {
                const int slot = (ks * 4 + (l >> 4)) ^ (ar & 7);
                af[m][ks] = *reinterpret_cast<const bf16x8*>(
                    (const char*)sA + ar * 128 + slot * 16);
            }
        }
#pragma unroll
        for (int n = 0; n < 4; ++n) {
            const int br = wc * 64 + n * 16 + (l & 15);
#pragma unroll
            for (int ks = 0; ks < 2; ++ks) {
                const int slot = (ks * 4 + (l >> 4)) ^ (br & 7);
                bfv[n][ks] = *reinterpret_cast<const bf16x8*>(
                    (const char*)sB + br * 128 + slot * 16);
            }
        }
#pragma unroll
        for (int ks = 0; ks < 2; ++ks)
#pragma unroll
            for (int m = 0; m < 4; ++m)
#pragma unroll
                for (int n = 0; n < 4; ++n)
                    acc[m][n] = __builtin_amdgcn_mfma_f32_16x16x32_bf16(
                        af[m][ks], bfv[n][ks], acc[m][n], 0, 0, 0);
        __syncthreads();
    }

    const int cl = l & 15;
    if constexpr (sizeof(CT) == 2) {
        ushort* st = smem;   // [128][128] bf16 bounce
#pragma unroll
        for (int n = 0; n < 4; ++n) {
            const int col = wc * 64 + n * 16 + cl;
            const float bv = HAS_BIAS ? bias[bCol + col] : 0.f;
#pragma unroll
            for (int m = 0; m < 4; ++m) {
                const int row0 = wr * 64 + m * 16 + (l >> 4) * 4;
#pragma unroll
                for (int r = 0; r < 4; ++r)
                    st[(row0 + r) * 128 + col] = f2b((acc[m][n][r] + bv) * alpha);
            }
        }
        __syncthreads();
#pragma unroll
        for (int i = 0; i < 8; ++i) {
            const int c    = tid + i * 256;
            const int row  = c >> 4;
            const int col8 = (c & 15) * 8;
            *reinterpret_cast<uint4*>(
                (ushort*)C + (size_t)(bRow + row) * ldc + bCol + col8) =
                *reinterpret_cast<const uint4*>(st + row * 128 + col8);
        }
    } else {
#pragma unroll
        for (int n = 0; n < 4; ++n) {
            const int col = bCol + wc * 64 + n * 16 + cl;
            const float bv = HAS_BIAS ? bias[col] : 0.f;
#pragma unroll
            for (int m = 0; m < 4; ++m) {
#pragma unroll
                for (int r = 0; r < 4; ++r) {
                    const int row = bRow + wr * 64 + m * 16 + (l >> 4) * 4 + r;
                    ((float*)C)[(size_t)row * ldc + col] = (acc[m][n][r] + bv) * alpha;
                }
            }
        }
    }
}

// ---------------- in-place row softmax on bf16 [rows][2048] ----------------
__global__ __launch_bounds__(256) void softmax_rows(ushort* __restrict__ S)
{
    __shared__ float red[8];
    const size_t row = blockIdx.x;
    ushort* p = S + row * 2048;
    const int tid = threadIdx.x;

    uint4 v = reinterpret_cast<uint4*>(p)[tid];   // 8 bf16
    float f[8];
    const unsigned int* wv = reinterpret_cast<const unsigned int*>(&v);
#pragma unroll
    for (int j = 0; j < 4; ++j) {
        f[2 * j]     = b2f(wv[j] & 0xFFFFu);
        f[2 * j + 1] = b2f(wv[j] >> 16);
    }
    float mx = f[0];
#pragma unroll
    for (int j = 1; j < 8; ++j) mx = fmaxf(mx, f[j]);
#pragma unroll
    for (int s = 1; s < 64; s <<= 1) mx = fmaxf(mx, __shfl_xor(mx, s));
    if ((tid & 63) == 0) red[tid >> 6] = mx;
    __syncthreads();
    mx = fmaxf(fmaxf(red[0], red[1]), fmaxf(red[2], red[3]));

    float sum = 0.f;
#pragma unroll
    for (int j = 0; j < 8; ++j) { f[j] = __expf(f[j] - mx); sum += f[j]; }
#pragma unroll
    for (int s = 1; s < 64; s <<= 1) sum += __shfl_xor(sum, s);
    if ((tid & 63) == 0) red[4 + (tid >> 6)] = sum;
    __syncthreads();
    sum = (red[4] + red[5]) + (red[6] + red[7]);
    const float inv = 1.0f / sum;

    uint4 o;
    unsigned int* wo = reinterpret_cast<unsigned int*>(&o);
#pragma unroll
    for (int j = 0; j < 4; ++j) {
        const unsigned int lo = f2b(f[2 * j] * inv);
        const unsigned int hi = f2b(f[2 * j + 1] * inv);
        wo[j] = lo | (hi << 16);
    }
    reinterpret_cast<uint4*>(p)[tid] = o;
}

// ---------------- tiled bf16 transpose: V[b][s][ld] -> Vt[b][e][s] ----------
__global__ __launch_bounds__(256) void transpose_v(
    const ushort* __restrict__ V, ushort* __restrict__ Vt, int ldv, long strideV)
{
    __shared__ ushort t[64][65];
    const int b  = blockIdx.z;
    const int e0 = blockIdx.x * 64;
    const int s0 = blockIdx.y * 64;
    const int tid = threadIdx.x;
    const int cg = (tid & 15) * 4;
    const int r0 = tid >> 4;

    const ushort* Vb = V + (size_t)b * strideV;
#pragma unroll
    for (int p = 0; p < 4; ++p) {
        const int r = r0 + p * 16;
        ushort4 x = *reinterpret_cast<const ushort4*>(
            Vb + (size_t)(s0 + r) * ldv + e0 + cg);
        t[r][cg + 0] = x.x; t[r][cg + 1] = x.y;
        t[r][cg + 2] = x.z; t[r][cg + 3] = x.w;
    }
    __syncthreads();
    ushort* Vtb = Vt + (size_t)b * 1024 * 2048;
#pragma unroll
    for (int p = 0; p < 4; ++p) {
        const int e = r0 + p * 16;
        ushort4 o;
        o.x = t[cg + 0][e]; o.y = t[cg + 1][e];
        o.z = t[cg + 2][e]; o.w = t[cg + 3][e];
        *reinterpret_cast<ushort4*>(Vtb + (size_t)(e0 + e) * 2048 + s0 + cg) = o;
    }
}

// ---------------- launch ----------------
extern "C" void kernel_launch(void* const* d_in, const int* in_sizes, int n_in,
                              void* d_out, int out_size, void* d_ws, size_t ws_size,
                              hipStream_t stream)
{
    const float* x  = (const float*)d_in[0];
    const float* Wq = (const float*)d_in[1];
    const float* bq = (const float*)d_in[2];
    const float* Wk = (const float*)d_in[3];
    const float* bk = (const float*)d_in[4];
    const float* Wv = (const float*)d_in[5];
    const float* bv = (const float*)d_in[6];
    const float* Wo = (const float*)d_in[7];
    const float* bo = (const float*)d_in[8];

    char* ws = (char*)d_ws;
    ushort* xb    = (ushort*)(ws);                 // 16 MB  [8192][1024]
    ushort* Wqkvb = (ushort*)(ws + 16777216);      // 8 MB   [Wq;Wk;Wv;Wo]
    ushort* Wob   = Wqkvb + 3 * 1048576;
    float*  bqkv  = (float*) (ws + 25165824);      // 12 KB  [3072]
    ushort* QKVb  = (ushort*)(ws + 26214400);      // 48 MB  [8192][3072]
    ushort* Vtb   = (ushort*)(ws + 76546048);      // 16 MB  [4][1024][2048]
    ushort* Sb    = (ushort*)(ws + 93323264);      // 32 MB  [4][2048][2048]
    ushort* Ob    = (ushort*)(ws + 126877696);     // 16 MB  [8192][1024]

    prep<<<2048, 256, 0, stream>>>(x, Wq, Wk, Wv, Wo, bq, bk, bv, bqkv, xb, Wqkvb);

    // fused QKV projection: [8192,3072] = xb @ Wqkv^T + bqkv (256^2 kernel)
    gemm256_bt<true><<<dim3(12, 32, 1), 512, 0, stream>>>(
        xb, Wqkvb, bqkv, QKVb, 1024, 1024, 3072, 1024, 0, 0, 0, 1.0f);

    // V^T for the PV GEMM
    transpose_v<<<dim3(16, 32, 4), 256, 0, stream>>>(
        QKVb + 2048, Vtb, 3072, 2048L * 3072);

    // scores: per batch [2048,2048] = (Q @ K^T)/32 (256^2 kernel)
    gemm256_bt<false><<<dim3(8, 8, 4), 512, 0, stream>>>(
        QKVb, QKVb + 1024, nullptr, Sb, 3072, 3072, 2048, 1024,
        2048L * 3072, 2048L * 3072, 2048L * 2048, 0.03125f);

    // softmax rows, in place
    softmax_rows<<<8192, 256, 0, stream>>>(Sb);

    // O = P @ V : per batch [2048,1024] = Sb @ Vt^T (128^2 kernel)
    gemm_bt<ushort, false><<<dim3(8, 16, 4), 256, 0, stream>>>(
        Sb, Vtb, nullptr, Ob, 2048, 2048, 1024, 2048,
        2048L * 2048, 1024L * 2048, 2048L * 1024, 1.0f);

    // out = O @ Wo^T + bo (fp32, 128^2 kernel)
    gemm_bt<float, true><<<dim3(8, 64, 1), 256, 0, stream>>>(
        Ob, Wob, bo, (float*)d_out, 1024, 1024, 1024, 1024, 0, 0, 0, 1.0f);
}

// Round 8
// 289.203 us; speedup vs baseline: 1.0184x; 1.0184x over previous
//
#include <hip/hip_runtime.h>
#include <hip/hip_bf16.h>
#include <stdint.h>

typedef short bf16x8 __attribute__((ext_vector_type(8)));
typedef float f32x4 __attribute__((ext_vector_type(4)));
typedef __attribute__((address_space(3))) void lds_void_t;
typedef __attribute__((address_space(1))) void g_void_t;

static __device__ __forceinline__ unsigned short f2b(float f) {
    __hip_bfloat16 b = __float2bfloat16(f);
    return __builtin_bit_cast(unsigned short, b);
}
static __device__ __forceinline__ float b2f(unsigned int u) {
    return __builtin_bit_cast(float, u << 16);
}

// ---------------- fused prep: cast x + 4 weights to bf16, concat biases ----
__global__ __launch_bounds__(256) void prep(
    const float* __restrict__ x,
    const float* __restrict__ wq, const float* __restrict__ wk,
    const float* __restrict__ wv, const float* __restrict__ wo,
    const float* __restrict__ bq, const float* __restrict__ bk,
    const float* __restrict__ bv_, float* __restrict__ bqkv,
    ushort* __restrict__ xb, ushort* __restrict__ wqkvb)
{
    const int T = 3145728;  // float4 units: x 2097152 + 4 * 262144
    int i = blockIdx.x * 256 + threadIdx.x;
    const int stride = gridDim.x * 256;
    for (; i < T; i += stride) {
        const float* src; ushort* dst; int off;
        if (i < 2097152) { src = x; dst = xb; off = i; }
        else {
            const int j = i - 2097152;
            const int w = j >> 18;
            off = j & 262143;
            src = (w == 0) ? wq : (w == 1) ? wk : (w == 2) ? wv : wo;
            dst = wqkvb + (w << 20);
        }
        float4 v = reinterpret_cast<const float4*>(src)[off];
        ushort4 o;
        o.x = f2b(v.x); o.y = f2b(v.y); o.z = f2b(v.z); o.w = f2b(v.w);
        reinterpret_cast<ushort4*>(dst)[off] = o;
    }
    const int t = blockIdx.x * 256 + threadIdx.x;
    if (t < 3072) {
        const int sec = t >> 10, of = t & 1023;
        bqkv[t] = sec == 0 ? bq[of] : (sec == 1 ? bk[of] : bv_[of]);
    }
}

// ============ 256x256 8-wave bf16 GEMM, counted-vmcnt double buffer ========
// C = (A*B^T + bias)*alpha. A:[M][lda], B:[N][ldb] bf16 (K contiguous).
// Depth-2 pipeline: at top of tile t, issue all 8 global_load_lds for t+1
// into buf[cur^1] (its last readers passed the end-of-(t-1) barrier), then
// s_waitcnt vmcnt(8) -- waits ONLY tile-t's 8 loads; t+1's 8 stay in flight
// across the barrier (T4). No intra-tile barriers (tile phases only READ
// LDS; loads target the other buffer).
// Tiles with bCol >= vtCol write TRANSPOSED to Vt (b = bRow>>11, e = col -
// vtCol, s = bRow&2047 + row) instead of C  -> fuses the V^T production.
template<bool HAS_BIAS>
__global__ __launch_bounds__(512, 1)
void gemm256_bt(const ushort* __restrict__ A, const ushort* __restrict__ B,
                const float* __restrict__ bias, ushort* __restrict__ C,
                ushort* __restrict__ Vt, int vtCol,
                int lda, int ldb, int ldc, int K,
                long strideA, long strideB, long strideC, float alpha)
{
    __shared__ __align__(16) ushort smem[2][2][16384];   // [buf][A|B][256*64]

    const int bz = blockIdx.z;
    A += (size_t)bz * strideA;
    B += (size_t)bz * strideB;
    C += (size_t)bz * strideC;

    // XCD-aware bijective swizzle (T1)
    const int gx = gridDim.x, gy = gridDim.y;
    const int nwg = gx * gy;
    int bx = blockIdx.x, by = blockIdx.y;
    if ((nwg & 7) == 0) {
        const int flat = blockIdx.x + gx * blockIdx.y;
        const int cpx = nwg >> 3;
        const int u = (flat & 7) * cpx + (flat >> 3);
        bx = u % gx;
        by = u / gx;
    }

    const int tid = threadIdx.x;
    const int w   = tid >> 6;      // wave 0..7
    const int l   = tid & 63;
    const int wr  = w >> 2;        // 0..1  (M half)
    const int wc  = w & 3;         // 0..3  (N quarter)

    const int bRow = by * 256;
    const int bCol = bx * 256;

    // staging lane addressing: chunk = 8 rows x 64 k = 1KB;
    // LDS[row][slot16] = global[row][slot16 ^ (row&7)] via pre-swizzled src.
    const int lr   = l >> 3;
    const int scol = (((l & 7) ^ lr) << 3);

    f32x4 acc[8][4];
#pragma unroll
    for (int m = 0; m < 8; ++m)
#pragma unroll
        for (int n = 0; n < 4; ++n)
            acc[m][n] = f32x4{0.f, 0.f, 0.f, 0.f};

    const int NT = K >> 6;

    // prologue: issue tile 0's 8 loads into buf 0
#pragma unroll
    for (int p = 0; p < 4; ++p) {
        const int c = w * 4 + p;
        const ushort* gA = A + (size_t)(bRow + c * 8 + lr) * lda + scol;
        const ushort* gB = B + (size_t)(bCol + c * 8 + lr) * ldb + scol;
        __builtin_amdgcn_global_load_lds((const g_void_t*)gA,
            (lds_void_t*)((char*)&smem[0][0][0] + c * 1024), 16, 0, 0);
        __builtin_amdgcn_global_load_lds((const g_void_t*)gB,
            (lds_void_t*)((char*)&smem[0][1][0] + c * 1024), 16, 0, 0);
    }

    int cur = 0;
    bf16x8 af[4][2], bfr[2][2];
    for (int t = 0; t < NT; ++t) {
        const char* sAc = (const char*)&smem[cur][0][0];
        const char* sBc = (const char*)&smem[cur][1][0];
        char* sAn = (char*)&smem[cur ^ 1][0][0];
        char* sBn = (char*)&smem[cur ^ 1][1][0];

        if (t + 1 < NT) {
            // issue next tile's 8 loads; buf[cur^1]'s readers all passed the
            // previous end-of-tile barrier.
            const int k1 = (t + 1) << 6;
#pragma unroll
            for (int p = 0; p < 4; ++p) {
                const int c = w * 4 + p;
                const ushort* gA = A + (size_t)(bRow + c * 8 + lr) * lda + (k1 + scol);
                const ushort* gB = B + (size_t)(bCol + c * 8 + lr) * ldb + (k1 + scol);
                __builtin_amdgcn_global_load_lds((const g_void_t*)gA,
                    (lds_void_t*)(sAn + c * 1024), 16, 0, 0);
                __builtin_amdgcn_global_load_lds((const g_void_t*)gB,
                    (lds_void_t*)(sBn + c * 1024), 16, 0, 0);
            }
            asm volatile("s_waitcnt vmcnt(8)" ::: "memory");  // tile t's landed
        } else {
            asm volatile("s_waitcnt vmcnt(0)" ::: "memory");
        }
        __builtin_amdgcn_s_barrier();          // all waves' tile-t loads done
        __builtin_amdgcn_sched_barrier(0);
        asm volatile("" ::: "memory");

        // 4 zigzag quadrant phases, no barriers (reads only)
#pragma unroll
        for (int p = 0; p < 4; ++p) {
            const int mh = p >> 1;                      // 00,01,11,10
            const int nh = (p == 1 || p == 2) ? 1 : 0;
            if (p == 0 || p == 2) {
#pragma unroll
                for (int i = 0; i < 4; ++i) {
                    const int ar = wr * 128 + (mh * 4 + i) * 16 + (l & 15);
#pragma unroll
                    for (int ks = 0; ks < 2; ++ks) {
                        const int slot = (ks * 4 + (l >> 4)) ^ (ar & 7);
                        af[i][ks] = *reinterpret_cast<const bf16x8*>(
                            sAc + ar * 128 + slot * 16);
                    }
                }
            }
            if (p != 2) {
#pragma unroll
                for (int j = 0; j < 2; ++j) {
                    const int br = wc * 64 + (nh * 2 + j) * 16 + (l & 15);
#pragma unroll
                    for (int ks = 0; ks < 2; ++ks) {
                        const int slot = (ks * 4 + (l >> 4)) ^ (br & 7);
                        bfr[j][ks] = *reinterpret_cast<const bf16x8*>(
                            sBc + br * 128 + slot * 16);
                    }
                }
            }
            __builtin_amdgcn_s_setprio(1);
#pragma unroll
            for (int ks = 0; ks < 2; ++ks)
#pragma unroll
                for (int i = 0; i < 4; ++i)
#pragma unroll
                    for (int j = 0; j < 2; ++j)
                        acc[mh * 4 + i][nh * 2 + j] =
                            __builtin_amdgcn_mfma_f32_16x16x32_bf16(
                                af[i][ks], bfr[j][ks],
                                acc[mh * 4 + i][nh * 2 + j], 0, 0, 0);
            __builtin_amdgcn_s_setprio(0);
        }

        asm volatile("" ::: "memory");
        __builtin_amdgcn_sched_barrier(0);
        __builtin_amdgcn_s_barrier();          // all waves done reading buf[cur]
        cur ^= 1;
    }

    // ---------------- epilogue ----------------
    const int cl = l & 15;
    char* stb = (char*)smem;
    if (bCol >= vtCol) {
        // V tile: write TRANSPOSED to Vt[b][e][s].
        // st2 element (c=col,r=row) at byte c*512 + ((r*2) ^ ((c&7)<<4))
#pragma unroll
        for (int n = 0; n < 4; ++n) {
            const int col = wc * 64 + n * 16 + cl;
            const float bv = HAS_BIAS ? bias[bCol + col] : 0.f;
#pragma unroll
            for (int m = 0; m < 8; ++m) {
                const int row0 = wr * 128 + m * 16 + (l >> 4) * 4;
#pragma unroll
                for (int r = 0; r < 4; ++r) {
                    const int row = row0 + r;
                    *(ushort*)(stb + col * 512 + ((row * 2) ^ ((col & 7) << 4))) =
                        f2b((acc[m][n][r] + bv) * alpha);
                }
            }
        }
        __syncthreads();
        const int bb    = bRow >> 11;
        const int sBase = bRow & 2047;
        const int e0    = bCol - vtCol;
        ushort* Vtb = Vt + ((size_t)bb << 21);
#pragma unroll
        for (int i = 0; i < 16; ++i) {
            const int q  = tid + (i << 9);      // 0..8191 chunks of 16B
            const int c  = q >> 5;              // col (e_local)
            const int rq = (q & 31) << 4;       // byte offset along rows
            const uint4 v = *reinterpret_cast<const uint4*>(
                stb + c * 512 + (rq ^ ((c & 7) << 4)));
            *reinterpret_cast<uint4*>(
                Vtb + (size_t)(e0 + c) * 2048 + sBase + ((q & 31) << 3)) = v;
        }
    } else {
        // normal: swizzled LDS bounce then 16B coalesced stores
        ushort* st = (ushort*)smem;
#pragma unroll
        for (int n = 0; n < 4; ++n) {
            const int col = wc * 64 + n * 16 + cl;
            const float bv = HAS_BIAS ? bias[bCol + col] : 0.f;
#pragma unroll
            for (int m = 0; m < 8; ++m) {
                const int row0 = wr * 128 + m * 16 + (l >> 4) * 4;
#pragma unroll
                for (int r = 0; r < 4; ++r) {
                    const int row = row0 + r;
                    const int sl  = ((col >> 3) ^ (row & 7));
                    st[row * 256 + (sl << 3) + (col & 7)] =
                        f2b((acc[m][n][r] + bv) * alpha);
                }
            }
        }
        __syncthreads();
#pragma unroll
        for (int i = 0; i < 16; ++i) {
            const int c    = tid + (i << 9);
            const int row  = c >> 5;
            const int slot = (c & 31) ^ (row & 7);
            const uint4 v = *reinterpret_cast<const uint4*>(
                (const char*)st + row * 512 + slot * 16);
            *reinterpret_cast<uint4*>(
                C + (size_t)(bRow + row) * ldc + bCol + ((c & 31) << 3)) = v;
        }
    }
}

// ---------------- 128x128 bf16 GEMM (proven), C = (A*B^T + bias)*alpha ----
template<typename CT, bool HAS_BIAS>
__global__ __launch_bounds__(256, 4)
void gemm_bt(const ushort* __restrict__ A, const ushort* __restrict__ B,
             const float* __restrict__ bias, CT* __restrict__ C,
             int lda, int ldb, int ldc, int K,
             long strideA, long strideB, long strideC, float alpha)
{
    __shared__ __align__(16) ushort smem[128 * 64 * 2];   // 32 KB
    ushort* sA = smem;
    ushort* sB = smem + 128 * 64;

    const int bz = blockIdx.z;
    A += (size_t)bz * strideA;
    B += (size_t)bz * strideB;
    C += (size_t)bz * strideC;

    const int gx = gridDim.x, gy = gridDim.y;
    const int nwg = gx * gy;
    int bx = blockIdx.x, by = blockIdx.y;
    if ((nwg & 7) == 0) {
        const int flat = blockIdx.x + gx * blockIdx.y;
        const int cpx = nwg >> 3;
        const int u = (flat & 7) * cpx + (flat >> 3);
        bx = u % gx;
        by = u / gx;
    }

    const int tid = threadIdx.x;
    const int w   = tid >> 6;
    const int l   = tid & 63;
    const int wr  = w >> 1;
    const int wc  = w & 1;

    const int bRow = by * 128;
    const int bCol = bx * 128;

    const int lr   = l >> 3;
    const int scol = (((l & 7) ^ lr) << 3);

    f32x4 acc[4][4];
#pragma unroll
    for (int m = 0; m < 4; ++m)
#pragma unroll
        for (int n = 0; n < 4; ++n)
            acc[m][n] = f32x4{0.f, 0.f, 0.f, 0.f};

    for (int k0 = 0; k0 < K; k0 += 64) {
#pragma unroll
        for (int p = 0; p < 4; ++p) {
            const int c   = p * 4 + w;
            const int row = c * 8 + lr;
            const ushort* gA = A + (size_t)(bRow + row) * lda + (k0 + scol);
            const ushort* gB = B + (size_t)(bCol + row) * ldb + (k0 + scol);
            __builtin_amdgcn_global_load_lds((const g_void_t*)gA,
                (lds_void_t*)((char*)sA + c * 1024), 16, 0, 0);
            __builtin_amdgcn_global_load_lds((const g_void_t*)gB,
                (lds_void_t*)((char*)sB + c * 1024), 16, 0, 0);
        }
        __syncthreads();

        bf16x8 af[4][2], bfv[4][2];
#pragma unroll
        for (int m = 0; m < 4; ++m) {
            const int ar = wr * 64 + m * 16 + (l & 15);
#pragma unroll
            for (int ks = 0; ks < 2; ++ks) {
                const int slot = (ks * 4 + (l >> 4)) ^ (ar & 7);
                af[m][ks] = *reinterpret_cast<const bf16x8*>(
                    (const char*)sA + ar * 128 + slot * 16);
            }
        }
#pragma unroll
        for (int n = 0; n < 4; ++n) {
            const int br = wc * 64 + n * 16 + (l & 15);
#pragma unroll
            for (int ks = 0; ks < 2; ++ks) {
                const int slot = (ks * 4 + (l >> 4)) ^ (br & 7);
                bfv[n][ks] = *reinterpret_cast<const bf16x8*>(
                    (const char*)sB + br * 128 + slot * 16);
            }
        }
#pragma unroll
        for (int ks = 0; ks < 2; ++ks)
#pragma unroll
            for (int m = 0; m < 4; ++m)
#pragma unroll
                for (int n = 0; n < 4; ++n)
                    acc[m][n] = __builtin_amdgcn_mfma_f32_16x16x32_bf16(
                        af[m][ks], bfv[n][ks], acc[m][n], 0, 0, 0);
        __syncthreads();
    }

    const int cl = l & 15;
    if constexpr (sizeof(CT) == 2) {
        ushort* st = smem;   // [128][128] bf16 bounce
#pragma unroll
        for (int n = 0; n < 4; ++n) {
            const int col = wc * 64 + n * 16 + cl;
            const float bv = HAS_BIAS ? bias[bCol + col] : 0.f;
#pragma unroll
            for (int m = 0; m < 4; ++m) {
                const int row0 = wr * 64 + m * 16 + (l >> 4) * 4;
#pragma unroll
                for (int r = 0; r < 4; ++r)
                    st[(row0 + r) * 128 + col] = f2b((acc[m][n][r] + bv) * alpha);
            }
        }
        __syncthreads();
#pragma unroll
        for (int i = 0; i < 8; ++i) {
            const int c    = tid + i * 256;
            const int row  = c >> 4;
            const int col8 = (c & 15) * 8;
            *reinterpret_cast<uint4*>(
                (ushort*)C + (size_t)(bRow + row) * ldc + bCol + col8) =
                *reinterpret_cast<const uint4*>(st + row * 128 + col8);
        }
    } else {
#pragma unroll
        for (int n = 0; n < 4; ++n) {
            const int col = bCol + wc * 64 + n * 16 + cl;
            const float bv = HAS_BIAS ? bias[col] : 0.f;
#pragma unroll
            for (int m = 0; m < 4; ++m) {
#pragma unroll
                for (int r = 0; r < 4; ++r) {
                    const int row = bRow + wr * 64 + m * 16 + (l >> 4) * 4 + r;
                    ((float*)C)[(size_t)row * ldc + col] = (acc[m][n][r] + bv) * alpha;
                }
            }
        }
    }
}

// ---------------- in-place row softmax on bf16 [rows][2048] ----------------
__global__ __launch_bounds__(256) void softmax_rows(ushort* __restrict__ S)
{
    __shared__ float red[8];
    const size_t row = blockIdx.x;
    ushort* p = S + row * 2048;
    const int tid = threadIdx.x;

    uint4 v = reinterpret_cast<uint4*>(p)[tid];   // 8 bf16
    float f[8];
    const unsigned int* wv = reinterpret_cast<const unsigned int*>(&v);
#pragma unroll
    for (int j = 0; j < 4; ++j) {
        f[2 * j]     = b2f(wv[j] & 0xFFFFu);
        f[2 * j + 1] = b2f(wv[j] >> 16);
    }
    float mx = f[0];
#pragma unroll
    for (int j = 1; j < 8; ++j) mx = fmaxf(mx, f[j]);
#pragma unroll
    for (int s = 1; s < 64; s <<= 1) mx = fmaxf(mx, __shfl_xor(mx, s));
    if ((tid & 63) == 0) red[tid >> 6] = mx;
    __syncthreads();
    mx = fmaxf(fmaxf(red[0], red[1]), fmaxf(red[2], red[3]));

    float sum = 0.f;
#pragma unroll
    for (int j = 0; j < 8; ++j) { f[j] = __expf(f[j] - mx); sum += f[j]; }
#pragma unroll
    for (int s = 1; s < 64; s <<= 1) sum += __shfl_xor(sum, s);
    if ((tid & 63) == 0) red[4 + (tid >> 6)] = sum;
    __syncthreads();
    sum = (red[4] + red[5]) + (red[6] + red[7]);
    const float inv = 1.0f / sum;

    uint4 o;
    unsigned int* wo = reinterpret_cast<unsigned int*>(&o);
#pragma unroll
    for (int j = 0; j < 4; ++j) {
        const unsigned int lo = f2b(f[2 * j] * inv);
        const unsigned int hi = f2b(f[2 * j + 1] * inv);
        wo[j] = lo | (hi << 16);
    }
    reinterpret_cast<uint4*>(p)[tid] = o;
}

// ---------------- launch ----------------
extern "C" void kernel_launch(void* const* d_in, const int* in_sizes, int n_in,
                              void* d_out, int out_size, void* d_ws, size_t ws_size,
                              hipStream_t stream)
{
    const float* x  = (const float*)d_in[0];
    const float* Wq = (const float*)d_in[1];
    const float* bq = (const float*)d_in[2];
    const float* Wk = (const float*)d_in[3];
    const float* bk = (const float*)d_in[4];
    const float* Wv = (const float*)d_in[5];
    const float* bv = (const float*)d_in[6];
    const float* Wo = (const float*)d_in[7];
    const float* bo = (const float*)d_in[8];

    char* ws = (char*)d_ws;
    ushort* xb    = (ushort*)(ws);                 // 16 MB  [8192][1024]
    ushort* Wqkvb = (ushort*)(ws + 16777216);      // 8 MB   [Wq;Wk;Wv;Wo]
    ushort* Wob   = Wqkvb + 3 * 1048576;
    float*  bqkv  = (float*) (ws + 25165824);      // 12 KB  [3072]
    ushort* QKVb  = (ushort*)(ws + 26214400);      // 48 MB  [8192][3072] (V third unused)
    ushort* Vtb   = (ushort*)(ws + 76546048);      // 16 MB  [4][1024][2048]
    ushort* Sb    = (ushort*)(ws + 93323264);      // 32 MB  [4][2048][2048]
    ushort* Ob    = (ushort*)(ws + 126877696);     // 16 MB  [8192][1024]

    prep<<<2048, 256, 0, stream>>>(x, Wq, Wk, Wv, Wo, bq, bk, bv, bqkv, xb, Wqkvb);

    // fused QKV projection; V tiles (col>=2048) written transposed to Vtb
    gemm256_bt<true><<<dim3(12, 32, 1), 512, 0, stream>>>(
        xb, Wqkvb, bqkv, QKVb, Vtb, 2048,
        1024, 1024, 3072, 1024, 0, 0, 0, 1.0f);

    // scores: per batch [2048,2048] = (Q @ K^T)/32
    gemm256_bt<false><<<dim3(8, 8, 4), 512, 0, stream>>>(
        QKVb, QKVb + 1024, nullptr, Sb, nullptr, 1 << 30,
        3072, 3072, 2048, 1024,
        2048L * 3072, 2048L * 3072, 2048L * 2048, 0.03125f);

    // softmax rows, in place
    softmax_rows<<<8192, 256, 0, stream>>>(Sb);

    // O = P @ V : per batch [2048,1024] = Sb @ Vt^T (128^2 kernel)
    gemm_bt<ushort, false><<<dim3(8, 16, 4), 256, 0, stream>>>(
        Sb, Vtb, nullptr, Ob, 2048, 2048, 1024, 2048,
        2048L * 2048, 1024L * 2048, 2048L * 1024, 1.0f);

    // out = O @ Wo^T + bo (fp32, 128^2 kernel)
    gemm_bt<float, true><<<dim3(8, 64, 1), 256, 0, stream>>>(
        Ob, Wob, bo, (float*)d_out, 1024, 1024, 1024, 1024, 0, 0, 0, 1.0f);
}

// Round 9
// 286.160 us; speedup vs baseline: 1.0292x; 1.0106x over previous
//
#include <hip/hip_runtime.h>
#include <hip/hip_bf16.h>
#include <stdint.h>

typedef short bf16x8 __attribute__((ext_vector_type(8)));
typedef float f32x4 __attribute__((ext_vector_type(4)));
typedef __attribute__((address_space(3))) void lds_void_t;
typedef __attribute__((address_space(1))) void g_void_t;

static __device__ __forceinline__ unsigned short f2b(float f) {
    __hip_bfloat16 b = __float2bfloat16(f);
    return __builtin_bit_cast(unsigned short, b);
}
static __device__ __forceinline__ float b2f(unsigned int u) {
    return __builtin_bit_cast(float, u << 16);
}

// ---------------- fused prep: cast x + 4 weights to bf16, concat biases ----
__global__ __launch_bounds__(256) void prep(
    const float* __restrict__ x,
    const float* __restrict__ wq, const float* __restrict__ wk,
    const float* __restrict__ wv, const float* __restrict__ wo,
    const float* __restrict__ bq, const float* __restrict__ bk,
    const float* __restrict__ bv_, float* __restrict__ bqkv,
    ushort* __restrict__ xb, ushort* __restrict__ wqkvb)
{
    const int T = 3145728;  // float4 units: x 2097152 + 4 * 262144
    int i = blockIdx.x * 256 + threadIdx.x;
    const int stride = gridDim.x * 256;
    for (; i < T; i += stride) {
        const float* src; ushort* dst; int off;
        if (i < 2097152) { src = x; dst = xb; off = i; }
        else {
            const int j = i - 2097152;
            const int w = j >> 18;
            off = j & 262143;
            src = (w == 0) ? wq : (w == 1) ? wk : (w == 2) ? wv : wo;
            dst = wqkvb + (w << 20);
        }
        float4 v = reinterpret_cast<const float4*>(src)[off];
        ushort4 o;
        o.x = f2b(v.x); o.y = f2b(v.y); o.z = f2b(v.z); o.w = f2b(v.w);
        reinterpret_cast<ushort4*>(dst)[off] = o;
    }
    const int t = blockIdx.x * 256 + threadIdx.x;
    if (t < 3072) {
        const int sec = t >> 10, of = t & 1023;
        bqkv[t] = sec == 0 ? bq[of] : (sec == 1 ? bk[of] : bv_[of]);
    }
}

// ======= 256x128 8-wave bf16 GEMM, depth-3 ring + spread counted-vmcnt =====
// C = (A*B^T + bias)*alpha.  A:[M][lda], B:[N][ldb] bf16 (K contiguous).
// Ring: buf[t%3] holds K-tile t (A 32KB + B 16KB = 48KB; 3 bufs = 144KB LDS).
// During tile t: 4 zigzag quadrant phases, each {ds_read frags | issue 1-2
// global_load_lds staging tile t+2 into buf[(t+2)%3] | setprio(1)+8 MFMA}.
// End of tile: vmcnt(6) (keeps t+2's 6 loads in flight, guarantees t+1's 6
// older loads landed), one s_barrier.  Write-after-read: buf[(t+2)%3] =
// buf[(t-1)%3], whose readers finished before the end-of-(t-1) barrier.
// Tiles with bCol >= vtCol write TRANSPOSED to Vt[b][e][s] (fused V^T).
template<bool HAS_BIAS>
__global__ __launch_bounds__(512, 1)
void gemm_k3(const ushort* __restrict__ A, const ushort* __restrict__ B,
             const float* __restrict__ bias, ushort* __restrict__ C,
             ushort* __restrict__ Vt, int vtCol,
             int lda, int ldb, int ldc, int K,
             long strideA, long strideB, long strideC, float alpha)
{
    __shared__ __align__(16) ushort smem[73728];   // 144KB = 3 x (16384 A + 8192 B)

    const int bz = blockIdx.z;
    A += (size_t)bz * strideA;
    B += (size_t)bz * strideB;
    C += (size_t)bz * strideC;

    // XCD-aware bijective swizzle (T1), per z-plane
    const int gx = gridDim.x, gy = gridDim.y;
    const int nwg = gx * gy;
    int bx = blockIdx.x, by = blockIdx.y;
    if ((nwg & 7) == 0) {
        const int flat = blockIdx.x + gx * blockIdx.y;
        const int cpx = nwg >> 3;
        const int u = (flat & 7) * cpx + (flat >> 3);
        bx = u % gx;
        by = u / gx;
    }

    const int tid = threadIdx.x;
    const int w   = tid >> 6;      // wave 0..7
    const int l   = tid & 63;
    const int wr  = w >> 1;        // 0..3  (M quarter, 64 rows)
    const int wc  = w & 1;         // 0..1  (N half, 64 cols)

    const int bRow = by * 256;
    const int bCol = bx * 128;

    // staging: chunk = 8 rows x 64 k = 1KB; LDS[row][slot16] =
    // global[row][slot16 ^ (row&7)] via pre-swizzled global source.
    const int lr   = l >> 3;
    const int scol = (((l & 7) ^ lr) << 3);
    // wave w owns A-chunks {4w..4w+3} (rows 32w..32w+31) and B-chunks {2w,2w+1}
    const int rowA = w * 32 + lr;          // + chunk-within-wave * 8
    const int rowB = w * 16 + lr;

    f32x4 acc[4][4];
#pragma unroll
    for (int m = 0; m < 4; ++m)
#pragma unroll
        for (int n = 0; n < 4; ++n)
            acc[m][n] = f32x4{0.f, 0.f, 0.f, 0.f};

    const int NT = K >> 6;

#define STAGE_A(kt, rs, i)                                                      \
    __builtin_amdgcn_global_load_lds(                                           \
        (const g_void_t*)(A + (size_t)(bRow + rowA + (i) * 8) * lda +           \
                          (((kt) << 6) + scol)),                                \
        (lds_void_t*)((char*)smem + (rs) * 49152 + (w * 4 + (i)) * 1024 +       \
                      l * 16), 16, 0, 0)
#define STAGE_B(kt, rs, j)                                                      \
    __builtin_amdgcn_global_load_lds(                                           \
        (const g_void_t*)(B + (size_t)(bCol + rowB + (j) * 8) * ldb +           \
                          (((kt) << 6) + scol)),                                \
        (lds_void_t*)((char*)smem + (rs) * 49152 + 32768 +                      \
                      (w * 2 + (j)) * 1024 + l * 16), 16, 0, 0)

    // prologue: stage tiles 0 and 1 (6 loads each per wave)
#pragma unroll
    for (int kt = 0; kt < 2; ++kt) {
        STAGE_A(kt, kt, 0); STAGE_A(kt, kt, 1);
        STAGE_A(kt, kt, 2); STAGE_A(kt, kt, 3);
        STAGE_B(kt, kt, 0); STAGE_B(kt, kt, 1);
    }
    asm volatile("s_waitcnt vmcnt(6)" ::: "memory");   // tile 0 landed
    __builtin_amdgcn_sched_barrier(0);
    __builtin_amdgcn_s_barrier();
    __builtin_amdgcn_sched_barrier(0);
    asm volatile("" ::: "memory");

    int r0 = 0;
    bf16x8 af[2][2], bf[4][2];
    for (int t = 0; t < NT; ++t) {
        int r2 = r0 + 2; if (r2 >= 3) r2 -= 3;
        const char* cAb = (const char*)smem + r0 * 49152;
        const char* cBb = cAb + 32768;
        const bool st = (t + 2 < NT);
        const int kt2 = t + 2;

#pragma unroll
        for (int p = 0; p < 4; ++p) {
            const int mh = p >> 1;                     // zigzag 00,01,11,10
            const int nh = (p == 1 || p == 2) ? 1 : 0;
            if (p == 0) {                              // A frags m=0,1
#pragma unroll
                for (int i = 0; i < 2; ++i) {
                    const int ar = wr * 64 + i * 16 + (l & 15);
#pragma unroll
                    for (int ks = 0; ks < 2; ++ks) {
                        const int slot = (ks * 4 + (l >> 4)) ^ (ar & 7);
                        af[i][ks] = *reinterpret_cast<const bf16x8*>(
                            cAb + ar * 128 + slot * 16);
                    }
                }
#pragma unroll
                for (int n = 0; n < 2; ++n) {          // B frags n=0,1
                    const int br = wc * 64 + n * 16 + (l & 15);
#pragma unroll
                    for (int ks = 0; ks < 2; ++ks) {
                        const int slot = (ks * 4 + (l >> 4)) ^ (br & 7);
                        bf[n][ks] = *reinterpret_cast<const bf16x8*>(
                            cBb + br * 128 + slot * 16);
                    }
                }
            } else if (p == 1) {                       // B frags n=2,3
#pragma unroll
                for (int n = 2; n < 4; ++n) {
                    const int br = wc * 64 + n * 16 + (l & 15);
#pragma unroll
                    for (int ks = 0; ks < 2; ++ks) {
                        const int slot = (ks * 4 + (l >> 4)) ^ (br & 7);
                        bf[n][ks] = *reinterpret_cast<const bf16x8*>(
                            cBb + br * 128 + slot * 16);
                    }
                }
            } else if (p == 2) {                       // A frags m=2,3
#pragma unroll
                for (int i = 0; i < 2; ++i) {
                    const int ar = wr * 64 + (2 + i) * 16 + (l & 15);
#pragma unroll
                    for (int ks = 0; ks < 2; ++ks) {
                        const int slot = (ks * 4 + (l >> 4)) ^ (ar & 7);
                        af[i][ks] = *reinterpret_cast<const bf16x8*>(
                            cAb + ar * 128 + slot * 16);
                    }
                }
            }
            // spread staging of tile t+2 (2,2,1,1 loads across phases)
            if (st) {
                if (p == 0)      { STAGE_A(kt2, r2, 0); STAGE_B(kt2, r2, 0); }
                else if (p == 1) { STAGE_A(kt2, r2, 1); STAGE_B(kt2, r2, 1); }
                else if (p == 2) { STAGE_A(kt2, r2, 2); }
                else             { STAGE_A(kt2, r2, 3); }
            }
            __builtin_amdgcn_s_setprio(1);
#pragma unroll
            for (int ks = 0; ks < 2; ++ks)
#pragma unroll
                for (int im = 0; im < 2; ++im)
#pragma unroll
                    for (int in_ = 0; in_ < 2; ++in_)
                        acc[mh * 2 + im][nh * 2 + in_] =
                            __builtin_amdgcn_mfma_f32_16x16x32_bf16(
                                af[im][ks], bf[nh * 2 + in_][ks],
                                acc[mh * 2 + im][nh * 2 + in_], 0, 0, 0);
            __builtin_amdgcn_s_setprio(0);
        }

        if (st) asm volatile("s_waitcnt vmcnt(6)" ::: "memory");
        else    asm volatile("s_waitcnt vmcnt(0)" ::: "memory");
        __builtin_amdgcn_sched_barrier(0);
        __builtin_amdgcn_s_barrier();
        __builtin_amdgcn_sched_barrier(0);
        asm volatile("" ::: "memory");
        r0 = (r0 + 1 == 3) ? 0 : r0 + 1;
    }
#undef STAGE_A
#undef STAGE_B

    // ---------------- epilogue (256x128 tile, 64KB bounce in smem) --------
    const int cl = l & 15;
    char* stb = (char*)smem;
    if (bCol >= vtCol) {
        // V tile: write TRANSPOSED to Vt[b][e][s].
        // st2 element (c=col 0..127, r=row 0..255) at byte c*512 + ((r*2)^((c&7)<<4))
#pragma unroll
        for (int n = 0; n < 4; ++n) {
            const int col = wc * 64 + n * 16 + cl;
            const float bv = HAS_BIAS ? bias[bCol + col] : 0.f;
#pragma unroll
            for (int m = 0; m < 4; ++m) {
                const int row0 = wr * 64 + m * 16 + (l >> 4) * 4;
#pragma unroll
                for (int r = 0; r < 4; ++r) {
                    const int row = row0 + r;
                    *(ushort*)(stb + col * 512 + ((row * 2) ^ ((col & 7) << 4))) =
                        f2b((acc[m][n][r] + bv) * alpha);
                }
            }
        }
        __syncthreads();
        const int bb    = bRow >> 11;
        const int sBase = bRow & 2047;
        const int e0    = bCol - vtCol;
        ushort* Vtb = Vt + ((size_t)bb << 21);
#pragma unroll
        for (int i = 0; i < 8; ++i) {
            const int q  = tid + (i << 9);      // 0..4095 chunks of 16B
            const int c  = q >> 5;              // col (e_local) 0..127
            const int rq = (q & 31) << 4;       // byte offset along rows
            const uint4 v = *reinterpret_cast<const uint4*>(
                stb + c * 512 + (rq ^ ((c & 7) << 4)));
            *reinterpret_cast<uint4*>(
                Vtb + (size_t)(e0 + c) * 2048 + sBase + ((q & 31) << 3)) = v;
        }
    } else {
        // normal: swizzled LDS bounce then 16B coalesced stores
        ushort* st = (ushort*)smem;             // [256][128] bf16, slot-swizzled
#pragma unroll
        for (int n = 0; n < 4; ++n) {
            const int col = wc * 64 + n * 16 + cl;
            const float bv = HAS_BIAS ? bias[bCol + col] : 0.f;
#pragma unroll
            for (int m = 0; m < 4; ++m) {
                const int row0 = wr * 64 + m * 16 + (l >> 4) * 4;
#pragma unroll
                for (int r = 0; r < 4; ++r) {
                    const int row = row0 + r;
                    const int sl  = ((col >> 3) ^ (row & 7)) & 15;
                    st[row * 128 + (sl << 3) + (col & 7)] =
                        f2b((acc[m][n][r] + bv) * alpha);
                }
            }
        }
        __syncthreads();
#pragma unroll
        for (int i = 0; i < 8; ++i) {
            const int c    = tid + (i << 9);    // 0..4095, 16 chunks per row
            const int row  = c >> 4;
            const int slot = ((c & 15) ^ (row & 7)) & 15;
            const uint4 v = *reinterpret_cast<const uint4*>(
                (const char*)st + row * 256 + slot * 16);
            *reinterpret_cast<uint4*>(
                C + (size_t)(bRow + row) * ldc + bCol + ((c & 15) << 3)) = v;
        }
    }
}

// ---------------- 128x128 bf16 GEMM (proven), C = (A*B^T + bias)*alpha ----
template<typename CT, bool HAS_BIAS>
__global__ __launch_bounds__(256, 4)
void gemm_bt(const ushort* __restrict__ A, const ushort* __restrict__ B,
             const float* __restrict__ bias, CT* __restrict__ C,
             int lda, int ldb, int ldc, int K,
             long strideA, long strideB, long strideC, float alpha)
{
    __shared__ __align__(16) ushort smem[128 * 64 * 2];   // 32 KB
    ushort* sA = smem;
    ushort* sB = smem + 128 * 64;

    const int bz = blockIdx.z;
    A += (size_t)bz * strideA;
    B += (size_t)bz * strideB;
    C += (size_t)bz * strideC;

    const int gx = gridDim.x, gy = gridDim.y;
    const int nwg = gx * gy;
    int bx = blockIdx.x, by = blockIdx.y;
    if ((nwg & 7) == 0) {
        const int flat = blockIdx.x + gx * blockIdx.y;
        const int cpx = nwg >> 3;
        const int u = (flat & 7) * cpx + (flat >> 3);
        bx = u % gx;
        by = u / gx;
    }

    const int tid = threadIdx.x;
    const int w   = tid >> 6;
    const int l   = tid & 63;
    const int wr  = w >> 1;
    const int wc  = w & 1;

    const int bRow = by * 128;
    const int bCol = bx * 128;

    const int lr   = l >> 3;
    const int scol = (((l & 7) ^ lr) << 3);

    f32x4 acc[4][4];
#pragma unroll
    for (int m = 0; m < 4; ++m)
#pragma unroll
        for (int n = 0; n < 4; ++n)
            acc[m][n] = f32x4{0.f, 0.f, 0.f, 0.f};

    for (int k0 = 0; k0 < K; k0 += 64) {
#pragma unroll
        for (int p = 0; p < 4; ++p) {
            const int c   = p * 4 + w;
            const int row = c * 8 + lr;
            const ushort* gA = A + (size_t)(bRow + row) * lda + (k0 + scol);
            const ushort* gB = B + (size_t)(bCol + row) * ldb + (k0 + scol);
            __builtin_amdgcn_global_load_lds((const g_void_t*)gA,
                (lds_void_t*)((char*)sA + c * 1024), 16, 0, 0);
            __builtin_amdgcn_global_load_lds((const g_void_t*)gB,
                (lds_void_t*)((char*)sB + c * 1024), 16, 0, 0);
        }
        __syncthreads();

        bf16x8 af[4][2], bfv[4][2];
#pragma unroll
        for (int m = 0; m < 4; ++m) {
            const int ar = wr * 64 + m * 16 + (l & 15);
#pragma unroll
            for (int ks = 0; ks < 2; ++ks) {
                const int slot = (ks * 4 + (l >> 4)) ^ (ar & 7);
                af[m][ks] = *reinterpret_cast<const bf16x8*>(
                    (const char*)sA + ar * 128 + slot * 16);
            }
        }
#pragma unroll
        for (int n = 0; n < 4; ++n) {
            const int br = wc * 64 + n * 16 + (l & 15);
#pragma unroll
            for (int ks = 0; ks < 2; ++ks) {
                const int slot = (ks * 4 + (l >> 4)) ^ (br & 7);
                bfv[n][ks] = *reinterpret_cast<const bf16x8*>(
                    (const char*)sB + br * 128 + slot * 16);
            }
        }
#pragma unroll
        for (int ks = 0; ks < 2; ++ks)
#pragma unroll
            for (int m = 0; m < 4; ++m)
#pragma unroll
                for (int n = 0; n < 4; ++n)
                    acc[m][n] = __builtin_amdgcn_mfma_f32_16x16x32_bf16(
                        af[m][ks], bfv[n][ks], acc[m][n], 0, 0, 0);
        __syncthreads();
    }

    const int cl = l & 15;
    if constexpr (sizeof(CT) == 2) {
        ushort* st = smem;   // [128][128] bf16 bounce
#pragma unroll
        for (int n = 0; n < 4; ++n) {
            const int col = wc * 64 + n * 16 + cl;
            const float bv = HAS_BIAS ? bias[bCol + col] : 0.f;
#pragma unroll
            for (int m = 0; m < 4; ++m) {
                const int row0 = wr * 64 + m * 16 + (l >> 4) * 4;
#pragma unroll
                for (int r = 0; r < 4; ++r)
                    st[(row0 + r) * 128 + col] = f2b((acc[m][n][r] + bv) * alpha);
            }
        }
        __syncthreads();
#pragma unroll
        for (int i = 0; i < 8; ++i) {
            const int c    = tid + i * 256;
            const int row  = c >> 4;
            const int col8 = (c & 15) * 8;
            *reinterpret_cast<uint4*>(
                (ushort*)C + (size_t)(bRow + row) * ldc + bCol + col8) =
                *reinterpret_cast<const uint4*>(st + row * 128 + col8);
        }
    } else {
#pragma unroll
        for (int n = 0; n < 4; ++n) {
            const int col = bCol + wc * 64 + n * 16 + cl;
            const float bv = HAS_BIAS ? bias[col] : 0.f;
#pragma unroll
            for (int m = 0; m < 4; ++m) {
#pragma unroll
                for (int r = 0; r < 4; ++r) {
                    const int row = bRow + wr * 64 + m * 16 + (l >> 4) * 4 + r;
                    ((float*)C)[(size_t)row * ldc + col] = (acc[m][n][r] + bv) * alpha;
                }
            }
        }
    }
}

// ---------------- in-place row softmax on bf16 [rows][2048] ----------------
__global__ __launch_bounds__(256) void softmax_rows(ushort* __restrict__ S)
{
    __shared__ float red[8];
    const size_t row = blockIdx.x;
    ushort* p = S + row * 2048;
    const int tid = threadIdx.x;

    uint4 v = reinterpret_cast<uint4*>(p)[tid];   // 8 bf16
    float f[8];
    const unsigned int* wv = reinterpret_cast<const unsigned int*>(&v);
#pragma unroll
    for (int j = 0; j < 4; ++j) {
        f[2 * j]     = b2f(wv[j] & 0xFFFFu);
        f[2 * j + 1] = b2f(wv[j] >> 16);
    }
    float mx = f[0];
#pragma unroll
    for (int j = 1; j < 8; ++j) mx = fmaxf(mx, f[j]);
#pragma unroll
    for (int s = 1; s < 64; s <<= 1) mx = fmaxf(mx, __shfl_xor(mx, s));
    if ((tid & 63) == 0) red[tid >> 6] = mx;
    __syncthreads();
    mx = fmaxf(fmaxf(red[0], red[1]), fmaxf(red[2], red[3]));

    float sum = 0.f;
#pragma unroll
    for (int j = 0; j < 8; ++j) { f[j] = __expf(f[j] - mx); sum += f[j]; }
#pragma unroll
    for (int s = 1; s < 64; s <<= 1) sum += __shfl_xor(sum, s);
    if ((tid & 63) == 0) red[4 + (tid >> 6)] = sum;
    __syncthreads();
    sum = (red[4] + red[5]) + (red[6] + red[7]);
    const float inv = 1.0f / sum;

    uint4 o;
    unsigned int* wo = reinterpret_cast<unsigned int*>(&o);
#pragma unroll
    for (int j = 0; j < 4; ++j) {
        const unsigned int lo = f2b(f[2 * j] * inv);
        const unsigned int hi = f2b(f[2 * j + 1] * inv);
        wo[j] = lo | (hi << 16);
    }
    reinterpret_cast<uint4*>(p)[tid] = o;
}

// ---------------- launch ----------------
extern "C" void kernel_launch(void* const* d_in, const int* in_sizes, int n_in,
                              void* d_out, int out_size, void* d_ws, size_t ws_size,
                              hipStream_t stream)
{
    const float* x  = (const float*)d_in[0];
    const float* Wq = (const float*)d_in[1];
    const float* bq = (const float*)d_in[2];
    const float* Wk = (const float*)d_in[3];
    const float* bk = (const float*)d_in[4];
    const float* Wv = (const float*)d_in[5];
    const float* bv = (const float*)d_in[6];
    const float* Wo = (const float*)d_in[7];
    const float* bo = (const float*)d_in[8];

    char* ws = (char*)d_ws;
    ushort* xb    = (ushort*)(ws);                 // 16 MB  [8192][1024]
    ushort* Wqkvb = (ushort*)(ws + 16777216);      // 8 MB   [Wq;Wk;Wv;Wo]
    ushort* Wob   = Wqkvb + 3 * 1048576;
    float*  bqkv  = (float*) (ws + 25165824);      // 12 KB  [3072]
    ushort* QKVb  = (ushort*)(ws + 26214400);      // 48 MB  [8192][3072] (V third unused)
    ushort* Vtb   = (ushort*)(ws + 76546048);      // 16 MB  [4][1024][2048]
    ushort* Sb    = (ushort*)(ws + 93323264);      // 32 MB  [4][2048][2048]
    ushort* Ob    = (ushort*)(ws + 126877696);     // 16 MB  [8192][1024]

    prep<<<2048, 256, 0, stream>>>(x, Wq, Wk, Wv, Wo, bq, bk, bv, bqkv, xb, Wqkvb);

    // fused QKV projection; V tiles (col>=2048) written transposed to Vtb
    gemm_k3<true><<<dim3(24, 32, 1), 512, 0, stream>>>(
        xb, Wqkvb, bqkv, QKVb, Vtb, 2048,
        1024, 1024, 3072, 1024, 0, 0, 0, 1.0f);

    // scores: per batch [2048,2048] = (Q @ K^T)/32
    gemm_k3<false><<<dim3(16, 8, 4), 512, 0, stream>>>(
        QKVb, QKVb + 1024, nullptr, Sb, nullptr, 1 << 30,
        3072, 3072, 2048, 1024,
        2048L * 3072, 2048L * 3072, 2048L * 2048, 0.03125f);

    // softmax rows, in place
    softmax_rows<<<8192, 256, 0, stream>>>(Sb);

    // O = P @ V : per batch [2048,1024] = Sb @ Vt^T
    gemm_k3<false><<<dim3(8, 8, 4), 512, 0, stream>>>(
        Sb, Vtb, nullptr, Ob, nullptr, 1 << 30,
        2048, 2048, 1024, 2048,
        2048L * 2048, 1024L * 2048, 2048L * 1024, 1.0f);

    // out = O @ Wo^T + bo (fp32, 128^2 kernel)
    gemm_bt<float, true><<<dim3(8, 64, 1), 256, 0, stream>>>(
        Ob, Wob, bo, (float*)d_out, 1024, 1024, 1024, 1024, 0, 0, 0, 1.0f);
}